// Round 8
// baseline (107.724 us; speedup 1.0000x reference)
//
#include <hip/hip_runtime.h>
#include <math.h>

#define KNN  20
#define INFK 0xFFFFFFFFu

typedef _Float16 half8 __attribute__((ext_vector_type(8)));
typedef float    f32x4 __attribute__((ext_vector_type(4)));

#define CE(a, b)                                                               \
    { unsigned _lo = ((a) < (b)) ? (a) : (b);                                  \
      unsigned _hi = ((a) < (b)) ? (b) : (a); (a) = _lo; (b) = _hi; }

__device__ __forceinline__ void sort4(unsigned (&v)[4]) {
    CE(v[0], v[1]); CE(v[2], v[3]); CE(v[0], v[2]); CE(v[1], v[3]); CE(v[1], v[2]);
}

// Batcher odd-even merge of two sorted 4-lists -> sorted 8
__device__ __forceinline__ void merge44(unsigned (&a)[4], unsigned (&b)[4],
                                        unsigned (&o)[8]) {
    CE(a[0], b[0]); CE(a[1], b[1]); CE(a[2], b[2]); CE(a[3], b[3]);
    CE(a[2], b[0]); CE(a[3], b[1]);
    CE(a[1], a[2]); CE(a[3], b[0]); CE(b[1], b[2]);
    o[0] = a[0]; o[1] = a[1]; o[2] = a[2]; o[3] = a[3];
    o[4] = b[0]; o[5] = b[1]; o[6] = b[2]; o[7] = b[3];
}

// ---- sorted-quad keep-4 DPP combine (proven R5) -----------------------------
// x0..x3 sorted asc per lane; partner quad pulled via DPP (t0..t3 sorted asc).
// (x0..x3, t3..t0) is bitonic; CE at distance 4 keeps the 4 smallest, 4-CE
// bitonic fixup re-sorts. Disabled/out-of-bounds source lanes receive
// old = -1 = INFK -> identity combine.
template <int CTRL, int RM>
__device__ __forceinline__ void quadmin_step(unsigned& x0, unsigned& x1,
                                             unsigned& x2, unsigned& x3) {
    const unsigned t0 = (unsigned)__builtin_amdgcn_update_dpp(-1, (int)x0, CTRL, RM, 0xf, false);
    const unsigned t1 = (unsigned)__builtin_amdgcn_update_dpp(-1, (int)x1, CTRL, RM, 0xf, false);
    const unsigned t2 = (unsigned)__builtin_amdgcn_update_dpp(-1, (int)x2, CTRL, RM, 0xf, false);
    const unsigned t3 = (unsigned)__builtin_amdgcn_update_dpp(-1, (int)x3, CTRL, RM, 0xf, false);
    unsigned c0 = (x0 < t3) ? x0 : t3;
    unsigned c1 = (x1 < t2) ? x1 : t2;
    unsigned c2 = (x2 < t1) ? x2 : t1;
    unsigned c3 = (x3 < t0) ? x3 : t0;
    CE(c0, c2); CE(c1, c3); CE(c0, c1); CE(c2, c3);
    x0 = c0; x1 = c1; x2 = c2; x3 = c3;
}

// Full-wave quad-min: 6 DPP levels (shr1/2/4/8 + bcast15 rm 0xa + bcast31
// rm 0xc -- the R2/R4-proven chain; accumulation cone covers each lane exactly
// once, so the keep-4 combine is exact). Lane 63 holds the global top-4.
__device__ __forceinline__ void wave_min4(unsigned x0, unsigned x1,
                                          unsigned x2, unsigned x3,
                                          unsigned (&wn)[4]) {
    quadmin_step<0x111, 0xf>(x0, x1, x2, x3);   // row_shr:1
    quadmin_step<0x112, 0xf>(x0, x1, x2, x3);   // row_shr:2
    quadmin_step<0x114, 0xf>(x0, x1, x2, x3);   // row_shr:4
    quadmin_step<0x118, 0xf>(x0, x1, x2, x3);   // row_shr:8
    quadmin_step<0x142, 0xa>(x0, x1, x2, x3);   // row_bcast:15 into rows 1,3
    quadmin_step<0x143, 0xc>(x0, x1, x2, x3);   // row_bcast:31 into rows 2,3
    wn[0] = (unsigned)__builtin_amdgcn_readlane((int)x0, 63);
    wn[1] = (unsigned)__builtin_amdgcn_readlane((int)x1, 63);
    wn[2] = (unsigned)__builtin_amdgcn_readlane((int)x2, 63);
    wn[3] = (unsigned)__builtin_amdgcn_readlane((int)x3, 63);
}

// conditional shift of an 8-list by cnt (1,2,4 decomposition); fills INFK.
__device__ __forceinline__ void shift8(unsigned (&cd)[8], int cnt) {
    const bool s1 = (cnt & 1) != 0;
    const bool s2 = (cnt & 2) != 0;
    const bool s4 = (cnt & 4) != 0;
    #pragma unroll
    for (int i = 0; i < 7; ++i) cd[i] = s1 ? cd[i + 1] : cd[i];
    cd[7] = s1 ? INFK : cd[7];
    #pragma unroll
    for (int i = 0; i < 6; ++i) cd[i] = s2 ? cd[i + 2] : cd[i];
    #pragma unroll
    for (int i = 6; i < 8; ++i) cd[i] = s2 ? INFK : cd[i];
    #pragma unroll
    for (int i = 0; i < 4; ++i) cd[i] = s4 ? cd[i + 4] : cd[i];
    #pragma unroll
    for (int i = 4; i < 8; ++i) cd[i] = s4 ? INFK : cd[i];
}

// 20-rank extraction, ONE row per wave: 5 quad-rounds on per-lane sorted-8.
// Winners ranks 4r..4r+3 land on lanes 4r..4r+3. Removal: any key <= 4th
// winner IS a winner (unique keys, exact threshold); cnt <= 4 per lane.
__device__ __forceinline__ int extract20(unsigned (&cd)[8], int t) {
    int nbr = 0;
    #pragma unroll
    for (int r = 0; r < 5; ++r) {
        unsigned wn[4];
        wave_min4(cd[0], cd[1], cd[2], cd[3], wn);
        nbr = (t == 4 * r    ) ? (int)(wn[0] & 511u) : nbr;
        nbr = (t == 4 * r + 1) ? (int)(wn[1] & 511u) : nbr;
        nbr = (t == 4 * r + 2) ? (int)(wn[2] & 511u) : nbr;
        nbr = (t == 4 * r + 3) ? (int)(wn[3] & 511u) : nbr;
        if (r < 4) {
            const int cnt = (int)(cd[0] <= wn[3]) + (int)(cd[1] <= wn[3]) +
                            (int)(cd[2] <= wn[3]) + (int)(cd[3] <= wn[3]);
            shift8(cd, cnt);
        }
    }
    return nbr;
}

// canonical 4-chain dot (register operands); staging/ssq path
__device__ __forceinline__ float dot16(const float4& o0, const float4& o1,
                                       const float4& o2, const float4& o3,
                                       const float4& a0, const float4& a1,
                                       const float4& a2, const float4& a3) {
    float d0 = 0.f, d1 = 0.f, d2 = 0.f, d3 = 0.f;
    d0 = fmaf(o0.x, a0.x, d0); d0 = fmaf(o0.y, a0.y, d0); d0 = fmaf(o0.z, a0.z, d0); d0 = fmaf(o0.w, a0.w, d0);
    d1 = fmaf(o1.x, a1.x, d1); d1 = fmaf(o1.y, a1.y, d1); d1 = fmaf(o1.z, a1.z, d1); d1 = fmaf(o1.w, a1.w, d1);
    d2 = fmaf(o2.x, a2.x, d2); d2 = fmaf(o2.y, a2.y, d2); d2 = fmaf(o2.z, a2.z, d2); d2 = fmaf(o2.w, a2.w, d2);
    d3 = fmaf(o3.x, a3.x, d3); d3 = fmaf(o3.y, a3.y, d3); d3 = fmaf(o3.z, a3.z, d3); d3 = fmaf(o3.w, a3.w, d3);
    return (d0 + d1) + (d2 + d3);
}

// same 4-chain dot, o held in SGPRs (wave-uniform query row). IEEE-identical
// to dot16 (same op order; operand bank is irrelevant to the result).
__device__ __forceinline__ float dot16s(const float (&os)[16],
                                        const float4& a0, const float4& a1,
                                        const float4& a2, const float4& a3) {
    float d0 = 0.f, d1 = 0.f, d2 = 0.f, d3 = 0.f;
    d0 = fmaf(os[0],  a0.x, d0); d0 = fmaf(os[1],  a0.y, d0); d0 = fmaf(os[2],  a0.z, d0); d0 = fmaf(os[3],  a0.w, d0);
    d1 = fmaf(os[4],  a1.x, d1); d1 = fmaf(os[5],  a1.y, d1); d1 = fmaf(os[6],  a1.z, d1); d1 = fmaf(os[7],  a1.w, d1);
    d2 = fmaf(os[8],  a2.x, d2); d2 = fmaf(os[9],  a2.y, d2); d2 = fmaf(os[10], a2.z, d2); d2 = fmaf(os[11], a2.w, d2);
    d3 = fmaf(os[12], a3.x, d3); d3 = fmaf(os[13], a3.y, d3); d3 = fmaf(os[14], a3.z, d3); d3 = fmaf(os[15], a3.w, d3);
    return (d0 + d1) + (d2 + d3);
}

__device__ __forceinline__ float rfl(float v) {
    return __int_as_float(__builtin_amdgcn_readfirstlane(__float_as_int(v)));
}

// ---------------------------------------------------------------------------
// Swizzled LDS tile, ONE point per thread (512 threads): point m at float
// index m*16, chunk c in slot ((c + (m>>1)) & 3). Same layout/bits as the
// previous 2-point staging; ssq computed from the staging registers with the
// identical dot16 chain.
// ---------------------------------------------------------------------------
__device__ __forceinline__ void stage_tile1(const float* __restrict__ src,
                                            float* __restrict__ Lx, int tid,
                                            float4 (&c)[4]) {
    const float4* s = (const float4*)(src + tid * 16);
    c[0] = s[0]; c[1] = s[1]; c[2] = s[2]; c[3] = s[3];
    const int r = (tid >> 1) & 3;
    float* wp = Lx + tid * 16;
    *(float4*)(wp + ((0 + r) & 3) * 4) = c[0];
    *(float4*)(wp + ((1 + r) & 3) * 4) = c[1];
    *(float4*)(wp + ((2 + r) & 3) * 4) = c[2];
    *(float4*)(wp + ((3 + r) & 3) * 4) = c[3];
}

// scalar element read from the swizzled tile (gather paths)
__device__ __forceinline__ float lds_elem(const float* __restrict__ Lx,
                                          int m, int d) {
    const int cc  = d >> 2;
    const int rot = (cc + (m >> 1)) & 3;
    return Lx[m * 16 + rot * 4 + (d & 3)];
}

// candidate scan, ONE row: 8 keys/lane -> sorted-8. Distance bits identical
// to all previous passing rounds (same chains, same inputs).
__device__ __forceinline__ void scan1_lds(const float* __restrict__ Lx,
                                          const float* __restrict__ ssq,
                                          float sqn, int t,
                                          const float (&os)[16],
                                          unsigned (&cd)[8]) {
    unsigned k0[4], k1[4];
    const int hrot = (t >> 1) & 3;
    const float* p0 = Lx + t * 16 + ((0 + hrot) & 3) * 4;
    const float* p1 = Lx + t * 16 + ((1 + hrot) & 3) * 4;
    const float* p2 = Lx + t * 16 + ((2 + hrot) & 3) * 4;
    const float* p3 = Lx + t * 16 + ((3 + hrot) & 3) * 4;
    #pragma unroll
    for (int j = 0; j < 8; ++j) {
        const int m = j * 64 + t;
        const float4 a0 = *(const float4*)(p0 + j * 1024);
        const float4 a1 = *(const float4*)(p1 + j * 1024);
        const float4 a2 = *(const float4*)(p2 + j * 1024);
        const float4 a3 = *(const float4*)(p3 + j * 1024);
        const float dot = dot16s(os, a0, a1, a2, a3);
        float vd = fmaxf(sqn + ssq[m] - 2.f * dot, 0.f);   // exact 0 at m==n
        const unsigned key = (__float_as_uint(vd) & 0xFFFFFE00u) | (unsigned)m;
        if (j < 4) k0[j] = key; else k1[j - 4] = key;
    }
    sort4(k0); sort4(k1);
    merge44(k0, k1, cd);
}

// load the wave-uniform query row into SGPRs
__device__ __forceinline__ void load_query_sgpr(const float* __restrict__ rowp,
                                                float (&os)[16]) {
    const float4* q4 = (const float4*)rowp;
    #pragma unroll
    for (int i = 0; i < 4; ++i) {
        const float4 v = q4[i];
        os[4 * i + 0] = rfl(v.x);
        os[4 * i + 1] = rfl(v.y);
        os[4 * i + 2] = rfl(v.z);
        os[4 * i + 3] = rfl(v.w);
    }
}

// ---------------------------------------------------------------------------
// Stage 1: 512-thread blocks (8 waves), ONE row per wave, 8 rows/block,
// grid 1024 (64 blocks/batch). 8192 waves total -> 32 waves/CU (vs 16): the
// row count caps wave parallelism, so 1 row/wave is the only full-occupancy
// shape. Query row lives in SGPRs (wave-uniform) to fit the 64-VGPR budget
// __launch_bounds__(512, 8) imposes. Block 0 builds the stage2 MFMA tables.
// ---------------------------------------------------------------------------
__global__ __launch_bounds__(512, 8)
void stage1_kernel(const float* __restrict__ x, const float* __restrict__ w_fm1,
                   const float* __restrict__ w_fm2, const float* __restrict__ w_mix1,
                   const float* __restrict__ w_mix2, const float* __restrict__ m_last,
                   const float* __restrict__ b_cls,
                   float* __restrict__ R, float* __restrict__ sqr,
                   half8* __restrict__ Bfrag, f32x4* __restrict__ Mfrag,
                   float* __restrict__ out) {
    __shared__ float4 LxV[2048];        // 32 KB swizzled point tile (+scratch)
    __shared__ float ssq[512];
    __shared__ float swn[KNN];
    float* Lx = (float*)LxV;

    const int tid   = threadIdx.x;
    const int bidx  = blockIdx.x;
    const int batch = bidx >> 6;
    const float* xb = x + (size_t)batch * 8192;

    if ((bidx & 63) == 0 && tid < 40)
        out[batch * 40 + tid] = b_cls[tid];

    if (tid < KNN) {
        float v[KNN]; float mx = -__builtin_inff();
        #pragma unroll
        for (int k = 0; k < KNN; ++k) { v[k] = w_fm1[k]; mx = fmaxf(mx, v[k]); }
        float s = 0.f;
        #pragma unroll
        for (int k = 0; k < KNN; ++k) { v[k] = __expf(v[k] - mx); s += v[k]; }
        swn[tid] = v[tid] / s;
    }

    if (bidx == 0) {
        // scratch layout inside Lx (consumed before the tile is staged):
        //   smix2 = Lx[0..1499], wcs = Lx[4096 + c*21 + k] (30x21)
        for (int e = tid; e < 1500; e += 512) Lx[e] = w_mix2[e];
        if (tid < 30) {
            float wr[KNN]; float mx = -__builtin_inff();
            #pragma unroll
            for (int k = 0; k < KNN; ++k) { wr[k] = w_fm2[tid * KNN + k]; mx = fmaxf(mx, wr[k]); }
            float s = 0.f;
            #pragma unroll
            for (int k = 0; k < KNN; ++k) { wr[k] = __expf(wr[k] - mx); s += wr[k]; }
            const float scale = w_mix1[tid] / s;
            #pragma unroll
            for (int k = 0; k < KNN; ++k) Lx[4096 + tid * 21 + k] = wr[k] * scale;
        }
    }
    __syncthreads();

    if (bidx == 0 && tid < 256) {
        // Per-lane fragment tables for stage2's mfma_f32_16x16x32_f16:
        //   A[m=lane&15][k=(lane>>4)*8+j], B[k=(lane>>4)*8+j][n=lane&15],
        //   C/D: col=lane&15, row=(lane>>4)*4+reg.  4 f-tiles x 64 lanes.
        const int lane = tid & 63, tile = tid >> 6;
        const int q = lane >> 4, c = lane & 15;
        const int f = tile * 16 + c;
        half8 hb;
        #pragma unroll
        for (int j = 0; j < 8; ++j) {
            const int k = q * 8 + j;
            float val = 0.f;
            if (k < KNN && f < 50) {
                #pragma unroll
                for (int cc = 0; cc < 30; ++cc)
                    val = fmaf(Lx[4096 + cc * 21 + k], Lx[cc * 50 + f], val);
            }
            hb[j] = (_Float16)val;
        }
        Bfrag[tile * 64 + lane] = hb;
        f32x4 mf;
        #pragma unroll
        for (int r = 0; r < 4; ++r) {
            const int d = q * 4 + r;
            mf[r] = (f < 50) ? m_last[d * 50 + f] : 0.f;
        }
        Mfrag[tile * 64 + lane] = mf;
    }
    __syncthreads();   // Lx scratch fully consumed before restage

    // stage points into swizzled LDS; ssq from the staging registers
    {
        float4 creg[4];
        stage_tile1(xb, Lx, tid, creg);
        ssq[tid] = dot16(creg[0], creg[1], creg[2], creg[3],
                         creg[0], creg[1], creg[2], creg[3]);
    }
    __syncthreads();

    const int t = tid & 63, w = tid >> 6;
    const int n0 = (bidx & 63) * 8 + w;          // this wave's row
    const size_t g0 = (size_t)batch * 512 + n0;

    float os[16];
    load_query_sgpr(xb + n0 * 16, os);
    const float sqn = rfl(ssq[n0]);

    unsigned cd[8];
    scan1_lds(Lx, ssq, sqn, t, os, cd);
    const int nbr = extract20(cd, t);            // lanes 0..19 hold ranks 0..19

    // gather from the LDS tile: lane covers e = j*64+t -> (k = e>>4, d = e&15)
    float nrf[5];
    #pragma unroll
    for (int j = 0; j < 5; ++j) {
        const int e = j * 64 + t;
        const int nb = __shfl(nbr, e >> 4, 64);
        nrf[j] = lds_elem(Lx, nb, e & 15);
    }
    // partial wFM: lane t sums its 5 k's for d = t&15 (k = j*4 + t>>4)
    const int kq = t >> 4;
    float part = 0.f;
    #pragma unroll
    for (int j = 0; j < 5; ++j) part = fmaf(swn[j * 4 + kq], nrf[j], part);
    part += __shfl_xor(part, 16, 64);
    part += __shfl_xor(part, 32, 64);
    const float racc = part;
    if (t < 16) R[g0 * 16 + t] = racc;

    // ||R||^2 with the SAME 4-chain grouping as dot16 (stage-2 diag -> exact 0)
    float p0 = 0.f, p1 = 0.f, p2 = 0.f, p3 = 0.f;
    #pragma unroll
    for (int d = 0; d < 4; ++d) {
        const float rv = __int_as_float(__builtin_amdgcn_readlane(__float_as_int(racc), d));
        p0 = fmaf(rv, rv, p0);
    }
    #pragma unroll
    for (int d = 4; d < 8; ++d) {
        const float rv = __int_as_float(__builtin_amdgcn_readlane(__float_as_int(racc), d));
        p1 = fmaf(rv, rv, p1);
    }
    #pragma unroll
    for (int d = 8; d < 12; ++d) {
        const float rv = __int_as_float(__builtin_amdgcn_readlane(__float_as_int(racc), d));
        p2 = fmaf(rv, rv, p2);
    }
    #pragma unroll
    for (int d = 12; d < 16; ++d) {
        const float rv = __int_as_float(__builtin_amdgcn_readlane(__float_as_int(racc), d));
        p3 = fmaf(rv, rv, p3);
    }
    if (t == 0) sqr[g0] = (p0 + p1) + (p2 + p3);
}

// ---------------------------------------------------------------------------
// Stage 2: same shape (512 thr, 1 row/wave, grid 1024). KNN on R + MFMA
// wFM2.mix2 + manifold dist + pool + classify.
// ---------------------------------------------------------------------------
__global__ __launch_bounds__(512, 8)
void stage2_kernel(const float* __restrict__ Rg, const float* __restrict__ sqr,
                   const half8* __restrict__ Bfrag, const f32x4* __restrict__ Mfrag,
                   const float* __restrict__ w_cls, float* __restrict__ out) {
    __shared__ float4 LrV[2048];        // 32 KB swizzled R tile
    __shared__ float ssq2[512];
    __shared__ float pool8[8];
    float* Lr = (float*)LrV;

    const int tid   = threadIdx.x;
    const int bidx  = blockIdx.x;
    const int batch = bidx >> 6;
    const float* Rb = Rg + (size_t)batch * 8192;
    const float* sb = sqr + batch * 512;

    ssq2[tid] = sb[tid];
    {
        float4 creg[4];
        stage_tile1(Rb, Lr, tid, creg);
    }
    __syncthreads();

    const int t = tid & 63, w = tid >> 6;
    const int n0 = (bidx & 63) * 8 + w;

    float os[16];
    load_query_sgpr(Rb + n0 * 16, os);
    const float sqn = rfl(ssq2[n0]);

    unsigned cd[8];
    scan1_lds(Lr, ssq2, sqn, t, os, cd);
    const int nbr = extract20(cd, t);

    // A-fragment straight from the tile: A[m=t&15][k=(t>>4)*8+j] = NR[k][m]
    // (nbr is 0 on non-rank lanes, so masked shfl sources stay in-bounds)
    const int q = t >> 4, c = t & 15;
    half8 af;
    #pragma unroll
    for (int j = 0; j < 8; ++j) {
        const int k = q * 8 + j;
        const int nb = __shfl(nbr, k & 31, 64);
        af[j] = (k < KNN) ? (_Float16)lds_elem(Lr, nb, c) : (_Float16)0.f;
    }

    // 4 f-tiles of 16: v = A(16x32) . B(32x16); dist accumulate
    float dsum = 0.f;
    #pragma unroll
    for (int tile = 0; tile < 4; ++tile) {
        const half8 bf = Bfrag[tile * 64 + t];
        const f32x4 mf = Mfrag[tile * 64 + t];
        f32x4 acc = {0.f, 0.f, 0.f, 0.f};
        acc = __builtin_amdgcn_mfma_f32_16x16x32_f16(af, bf, acc, 0, 0, 0);
        float a2 = 0.f;
        #pragma unroll
        for (int r = 0; r < 4; ++r) {
            const float diff = acc[r] - mf[r];
            a2 = fmaf(diff, diff, a2);
        }
        a2 += __shfl_xor(a2, 16, 64);
        a2 += __shfl_xor(a2, 32, 64);
        const int f = tile * 16 + c;
        dsum += (f < 50) ? sqrtf(a2 + 1e-8f) : 0.f;
    }
    // wave sum counts each f 4x (column replication) -> /4; pooled = /50
    #pragma unroll
    for (int off = 32; off >= 1; off >>= 1) dsum += __shfl_xor(dsum, off, 64);
    if (t == 0) pool8[w] = dsum * (1.0f / 200.0f);
    __syncthreads();

    if (tid < 40) {
        const int lb0 = (bidx & 63) * 8;
        float a = 0.f;
        #pragma unroll
        for (int i = 0; i < 8; ++i)
            a = fmaf(pool8[i], w_cls[(lb0 + i) * 40 + tid], a);
        unsafeAtomicAdd(&out[batch * 40 + tid], a);
    }
}

extern "C" void kernel_launch(void* const* d_in, const int* in_sizes, int n_in,
                              void* d_out, int out_size, void* d_ws, size_t ws_size,
                              hipStream_t stream) {
    const float* x      = (const float*)d_in[0];
    const float* w_fm1  = (const float*)d_in[1];
    const float* w_mix1 = (const float*)d_in[2];
    const float* w_fm2  = (const float*)d_in[3];
    const float* w_mix2 = (const float*)d_in[4];
    const float* m_last = (const float*)d_in[5];
    const float* w_cls  = (const float*)d_in[6];
    const float* b_cls  = (const float*)d_in[7];
    float* out = (float*)d_out;

    float* ws    = (float*)d_ws;
    float* R     = ws;                        // 131072 floats
    float* sqrb  = ws + 131072;               // 8192 floats
    half8* Bf    = (half8*)(ws + 139264);     // 256 x 16 B = 1024 floats
    f32x4* Mf    = (f32x4*)(ws + 140288);     // 256 x 16 B = 1024 floats

    stage1_kernel<<<1024, 512, 0, stream>>>(x, w_fm1, w_fm2, w_mix1, w_mix2,
                                            m_last, b_cls, R, sqrb, Bf, Mf, out);
    stage2_kernel<<<1024, 512, 0, stream>>>(R, sqrb, Bf, Mf, w_cls, out);
}

// Round 9
// 100.472 us; speedup vs baseline: 1.0722x; 1.0722x over previous
//
#include <hip/hip_runtime.h>
#include <math.h>

#define KNN  20
#define INFK 0xFFFFFFFFu

typedef _Float16 half8 __attribute__((ext_vector_type(8)));
typedef float    f32x4 __attribute__((ext_vector_type(4)));
typedef float    f32x2 __attribute__((ext_vector_type(2)));

#define CE(a, b)                                                               \
    { unsigned _lo = ((a) < (b)) ? (a) : (b);                                  \
      unsigned _hi = ((a) < (b)) ? (b) : (a); (a) = _lo; (b) = _hi; }

__device__ __forceinline__ void sort4(unsigned (&v)[4]) {
    CE(v[0], v[1]); CE(v[2], v[3]); CE(v[0], v[2]); CE(v[1], v[3]); CE(v[1], v[2]);
}

// Batcher odd-even merge of two sorted 4-lists -> sorted 8
__device__ __forceinline__ void merge44(unsigned (&a)[4], unsigned (&b)[4],
                                        unsigned (&o)[8]) {
    CE(a[0], b[0]); CE(a[1], b[1]); CE(a[2], b[2]); CE(a[3], b[3]);
    CE(a[2], b[0]); CE(a[3], b[1]);
    CE(a[1], a[2]); CE(a[3], b[0]); CE(b[1], b[2]);
    o[0] = a[0]; o[1] = a[1]; o[2] = a[2]; o[3] = a[3];
    o[4] = b[0]; o[5] = b[1]; o[6] = b[2]; o[7] = b[3];
}

// ---- sorted-quad keep-4 DPP combine (proven R5/R7) --------------------------
template <int CTRL, int RM>
__device__ __forceinline__ void quadmin_step(unsigned& x0, unsigned& x1,
                                             unsigned& x2, unsigned& x3) {
    const unsigned t0 = (unsigned)__builtin_amdgcn_update_dpp(-1, (int)x0, CTRL, RM, 0xf, false);
    const unsigned t1 = (unsigned)__builtin_amdgcn_update_dpp(-1, (int)x1, CTRL, RM, 0xf, false);
    const unsigned t2 = (unsigned)__builtin_amdgcn_update_dpp(-1, (int)x2, CTRL, RM, 0xf, false);
    const unsigned t3 = (unsigned)__builtin_amdgcn_update_dpp(-1, (int)x3, CTRL, RM, 0xf, false);
    unsigned c0 = (x0 < t3) ? x0 : t3;
    unsigned c1 = (x1 < t2) ? x1 : t2;
    unsigned c2 = (x2 < t1) ? x2 : t1;
    unsigned c3 = (x3 < t0) ? x3 : t0;
    CE(c0, c2); CE(c1, c3); CE(c0, c1); CE(c2, c3);
    x0 = c0; x1 = c1; x2 = c2; x3 = c3;
}

// Half-wave quad-min: 5 DPP levels; lane 31 = row A's top-4, lane 63 = row B's.
__device__ __forceinline__ void halfwave_min4(unsigned x0, unsigned x1,
                                              unsigned x2, unsigned x3,
                                              unsigned (&wl)[4], unsigned (&wh)[4]) {
    quadmin_step<0x111, 0xf>(x0, x1, x2, x3);   // row_shr:1
    quadmin_step<0x112, 0xf>(x0, x1, x2, x3);   // row_shr:2
    quadmin_step<0x114, 0xf>(x0, x1, x2, x3);   // row_shr:4
    quadmin_step<0x118, 0xf>(x0, x1, x2, x3);   // row_shr:8
    quadmin_step<0x142, 0xa>(x0, x1, x2, x3);   // row_bcast:15 into rows 1,3
    wl[0] = (unsigned)__builtin_amdgcn_readlane((int)x0, 31);
    wl[1] = (unsigned)__builtin_amdgcn_readlane((int)x1, 31);
    wl[2] = (unsigned)__builtin_amdgcn_readlane((int)x2, 31);
    wl[3] = (unsigned)__builtin_amdgcn_readlane((int)x3, 31);
    wh[0] = (unsigned)__builtin_amdgcn_readlane((int)x0, 63);
    wh[1] = (unsigned)__builtin_amdgcn_readlane((int)x1, 63);
    wh[2] = (unsigned)__builtin_amdgcn_readlane((int)x2, 63);
    wh[3] = (unsigned)__builtin_amdgcn_readlane((int)x3, 63);
}

// conditional shift of the leading LEN entries by cnt (1,2,4 decomposition)
template <int LEN>
__device__ __forceinline__ void shift_list(unsigned (&cd)[16], int cnt) {
    const bool s1 = (cnt & 1) != 0;
    const bool s2 = (cnt & 2) != 0;
    const bool s4 = (cnt & 4) != 0;
    #pragma unroll
    for (int i = 0; i < LEN - 1; ++i) cd[i] = s1 ? cd[i + 1] : cd[i];
    cd[LEN - 1] = s1 ? INFK : cd[LEN - 1];
    #pragma unroll
    for (int i = 0; i < LEN - 2; ++i) cd[i] = s2 ? cd[i + 2] : cd[i];
    #pragma unroll
    for (int i = LEN - 2; i < LEN; ++i) cd[i] = s2 ? INFK : cd[i];
    #pragma unroll
    for (int i = 0; i < LEN - 4; ++i) cd[i] = s4 ? cd[i + 4] : cd[i];
    #pragma unroll
    for (int i = LEN - 4; i < LEN; ++i) cd[i] = s4 ? INFK : cd[i];
}

// one extraction round: winners 4r..4r+3 of each half land on lanes (t&31).
template <int LEN>
__device__ __forceinline__ void round_extract(unsigned (&cd)[16], int t, int r,
                                              int& nbr, bool hi) {
    unsigned wl[4], wh[4];
    halfwave_min4(cd[0], cd[1], cd[2], cd[3], wl, wh);
    const unsigned w0 = hi ? wh[0] : wl[0];
    const unsigned w1 = hi ? wh[1] : wl[1];
    const unsigned w2 = hi ? wh[2] : wl[2];
    const unsigned w3 = hi ? wh[3] : wl[3];
    const int idx = t & 31;
    nbr = (idx == 4 * r    ) ? (int)(w0 & 511u) : nbr;
    nbr = (idx == 4 * r + 1) ? (int)(w1 & 511u) : nbr;
    nbr = (idx == 4 * r + 2) ? (int)(w2 & 511u) : nbr;
    nbr = (idx == 4 * r + 3) ? (int)(w3 & 511u) : nbr;
    if (LEN > 0) {
        const int cnt = (int)(cd[0] <= w3) + (int)(cd[1] <= w3) +
                        (int)(cd[2] <= w3) + (int)(cd[3] <= w3);
        shift_list<(LEN > 0 ? LEN : 16)>(cd, cnt);
    }
}

// 20-rank extraction in 5 quad-rounds on per-half sorted-16 lists.
__device__ __forceinline__ int extract20_half(unsigned (&cd)[16], int t) {
    int nbr = 0;
    const bool hi = (t >= 32);
    round_extract<16>(cd, t, 0, nbr, hi);
    round_extract<16>(cd, t, 1, nbr, hi);
    round_extract<12>(cd, t, 2, nbr, hi);
    round_extract<8> (cd, t, 3, nbr, hi);
    round_extract<0> (cd, t, 4, nbr, hi);
    return nbr;
}

// Redistribute halves + bitonic merge 8+8 -> sorted-16 per lane.
__device__ __forceinline__ void combine_half(const unsigned (&cdA)[8],
                                             const unsigned (&cdB)[8],
                                             bool hi, unsigned (&v)[16]) {
    unsigned snd[8], own[8], rcv[8];
    #pragma unroll
    for (int i = 0; i < 8; ++i) {
        snd[i] = hi ? cdA[i] : cdB[i];
        own[i] = hi ? cdB[i] : cdA[i];
    }
    #pragma unroll
    for (int i = 0; i < 8; ++i)
        rcv[i] = (unsigned)__shfl_xor((int)snd[i], 32, 64);
    #pragma unroll
    for (int i = 0; i < 8; ++i) { v[i] = own[i]; v[8 + i] = rcv[7 - i]; }
    #pragma unroll
    for (int i = 0; i < 8; ++i) CE(v[i], v[i + 8]);
    #pragma unroll
    for (int i = 0; i < 4; ++i) { CE(v[i], v[i + 4]); CE(v[i + 8], v[i + 12]); }
    #pragma unroll
    for (int b = 0; b < 16; b += 4) { CE(v[b], v[b + 2]); CE(v[b + 1], v[b + 3]); }
    #pragma unroll
    for (int p = 0; p < 16; p += 2) CE(v[p], v[p + 1]);
}

// canonical 4-chain dot; staging/ssq path (register operands)
__device__ __forceinline__ float dot16(const float4& o0, const float4& o1,
                                       const float4& o2, const float4& o3,
                                       const float4& a0, const float4& a1,
                                       const float4& a2, const float4& a3) {
    float d0 = 0.f, d1 = 0.f, d2 = 0.f, d3 = 0.f;
    d0 = fmaf(o0.x, a0.x, d0); d0 = fmaf(o0.y, a0.y, d0); d0 = fmaf(o0.z, a0.z, d0); d0 = fmaf(o0.w, a0.w, d0);
    d1 = fmaf(o1.x, a1.x, d1); d1 = fmaf(o1.y, a1.y, d1); d1 = fmaf(o1.z, a1.z, d1); d1 = fmaf(o1.w, a1.w, d1);
    d2 = fmaf(o2.x, a2.x, d2); d2 = fmaf(o2.y, a2.y, d2); d2 = fmaf(o2.z, a2.z, d2); d2 = fmaf(o2.w, a2.w, d2);
    d3 = fmaf(o3.x, a3.x, d3); d3 = fmaf(o3.y, a3.y, d3); d3 = fmaf(o3.z, a3.z, d3); d3 = fmaf(o3.w, a3.w, d3);
    return (d0 + d1) + (d2 + d3);
}

__device__ __forceinline__ f32x2 fma2(f32x2 a, f32x2 b, f32x2 c) {
    return __builtin_elementwise_fma(a, b, c);
}

// ---------------------------------------------------------------------------
// Swizzled LDS tile (unchanged R7 layout).
// ---------------------------------------------------------------------------
__device__ __forceinline__ void stage_tile(const float* __restrict__ src,
                                           float* __restrict__ Lx, int tid,
                                           float4 (&c)[8]) {
    const float4* s = (const float4*)(src + tid * 32);
    #pragma unroll
    for (int i = 0; i < 8; ++i) c[i] = s[i];
    const int r = tid & 3;
    float* wp = Lx + tid * 32;
    *(float4*)(wp +      ((0 + r) & 3) * 4) = c[0];
    *(float4*)(wp +      ((1 + r) & 3) * 4) = c[1];
    *(float4*)(wp +      ((2 + r) & 3) * 4) = c[2];
    *(float4*)(wp +      ((3 + r) & 3) * 4) = c[3];
    *(float4*)(wp + 16 + ((0 + r) & 3) * 4) = c[4];
    *(float4*)(wp + 16 + ((1 + r) & 3) * 4) = c[5];
    *(float4*)(wp + 16 + ((2 + r) & 3) * 4) = c[6];
    *(float4*)(wp + 16 + ((3 + r) & 3) * 4) = c[7];
}

__device__ __forceinline__ float lds_elem(const float* __restrict__ Lx,
                                          int m, int d) {
    const int cc  = d >> 2;
    const int rot = (cc + (m >> 1)) & 3;
    return Lx[m * 16 + rot * 4 + (d & 3)];
}

// candidate scan for TWO rows sharing every LDS read. Dot chains are computed
// with packed f32x2 FMA pairing row A (lane .x) with row B (lane .y): each
// half of v_pk_fma_f32 is an IEEE fma, so each row's chain keeps the exact
// canonical dot16 op order -> distance bits identical to all passing rounds.
__device__ __forceinline__ void scan2_lds(const float* __restrict__ Lx,
                                          const float* __restrict__ ssq,
                                          float sqnA, float sqnB, int t,
                                          const float4& oa0, const float4& oa1,
                                          const float4& oa2, const float4& oa3,
                                          const float4& ob0, const float4& ob1,
                                          const float4& ob2, const float4& ob3,
                                          unsigned (&cdA)[8], unsigned (&cdB)[8]) {
    unsigned kA0[4], kA1[4], kB0[4], kB1[4];
    const int hrot = (t >> 1) & 3;
    const float* p0 = Lx + t * 16 + ((0 + hrot) & 3) * 4;
    const float* p1 = Lx + t * 16 + ((1 + hrot) & 3) * 4;
    const float* p2 = Lx + t * 16 + ((2 + hrot) & 3) * 4;
    const float* p3 = Lx + t * 16 + ((3 + hrot) & 3) * 4;
    // loop-invariant multiplier pairs {oaE, obE}
    f32x2 op[16];
    op[0]  = (f32x2){oa0.x, ob0.x}; op[1]  = (f32x2){oa0.y, ob0.y};
    op[2]  = (f32x2){oa0.z, ob0.z}; op[3]  = (f32x2){oa0.w, ob0.w};
    op[4]  = (f32x2){oa1.x, ob1.x}; op[5]  = (f32x2){oa1.y, ob1.y};
    op[6]  = (f32x2){oa1.z, ob1.z}; op[7]  = (f32x2){oa1.w, ob1.w};
    op[8]  = (f32x2){oa2.x, ob2.x}; op[9]  = (f32x2){oa2.y, ob2.y};
    op[10] = (f32x2){oa2.z, ob2.z}; op[11] = (f32x2){oa2.w, ob2.w};
    op[12] = (f32x2){oa3.x, ob3.x}; op[13] = (f32x2){oa3.y, ob3.y};
    op[14] = (f32x2){oa3.z, ob3.z}; op[15] = (f32x2){oa3.w, ob3.w};
    #pragma unroll
    for (int j = 0; j < 8; ++j) {
        const int m = j * 64 + t;
        const float4 a0 = *(const float4*)(p0 + j * 1024);
        const float4 a1 = *(const float4*)(p1 + j * 1024);
        const float4 a2 = *(const float4*)(p2 + j * 1024);
        const float4 a3 = *(const float4*)(p3 + j * 1024);
        const float sm = ssq[m];
        f32x2 d0 = {0.f, 0.f}, d1 = {0.f, 0.f}, d2 = {0.f, 0.f}, d3 = {0.f, 0.f};
        d0 = fma2((f32x2){a0.x, a0.x}, op[0],  d0);
        d0 = fma2((f32x2){a0.y, a0.y}, op[1],  d0);
        d0 = fma2((f32x2){a0.z, a0.z}, op[2],  d0);
        d0 = fma2((f32x2){a0.w, a0.w}, op[3],  d0);
        d1 = fma2((f32x2){a1.x, a1.x}, op[4],  d1);
        d1 = fma2((f32x2){a1.y, a1.y}, op[5],  d1);
        d1 = fma2((f32x2){a1.z, a1.z}, op[6],  d1);
        d1 = fma2((f32x2){a1.w, a1.w}, op[7],  d1);
        d2 = fma2((f32x2){a2.x, a2.x}, op[8],  d2);
        d2 = fma2((f32x2){a2.y, a2.y}, op[9],  d2);
        d2 = fma2((f32x2){a2.z, a2.z}, op[10], d2);
        d2 = fma2((f32x2){a2.w, a2.w}, op[11], d2);
        d3 = fma2((f32x2){a3.x, a3.x}, op[12], d3);
        d3 = fma2((f32x2){a3.y, a3.y}, op[13], d3);
        d3 = fma2((f32x2){a3.z, a3.z}, op[14], d3);
        d3 = fma2((f32x2){a3.w, a3.w}, op[15], d3);
        const f32x2 s01 = d0 + d1;          // per-half IEEE adds == (d0+d1)
        const f32x2 s23 = d2 + d3;
        const f32x2 s   = s01 + s23;        // == (d0+d1)+(d2+d3) per row
        const float dotA = s.x;
        const float dotB = s.y;
        float vdA = fmaxf(sqnA + sm - 2.f * dotA, 0.f);   // exact 0 at m==n
        float vdB = fmaxf(sqnB + sm - 2.f * dotB, 0.f);
        const unsigned keyA = (__float_as_uint(vdA) & 0xFFFFFE00u) | (unsigned)m;
        const unsigned keyB = (__float_as_uint(vdB) & 0xFFFFFE00u) | (unsigned)m;
        if (j < 4) { kA0[j] = keyA; kB0[j] = keyB; }
        else       { kA1[j - 4] = keyA; kB1[j - 4] = keyB; }
    }
    sort4(kA0); sort4(kA1); sort4(kB0); sort4(kB1);
    merge44(kA0, kA1, cdA);
    merge44(kB0, kB1, cdB);
}

// full selection (R7 structure): scan -> halves -> 5-round quad extraction.
__device__ __forceinline__ int knn_select(const float* __restrict__ Lx,
                                          const float* __restrict__ ssq,
                                          float sqnA, float sqnB, int t,
                                          const float4& oa0, const float4& oa1,
                                          const float4& oa2, const float4& oa3,
                                          const float4& ob0, const float4& ob1,
                                          const float4& ob2, const float4& ob3) {
    unsigned cdA[8], cdB[8];
    scan2_lds(Lx, ssq, sqnA, sqnB, t,
              oa0, oa1, oa2, oa3, ob0, ob1, ob2, ob3, cdA, cdB);
    unsigned v[16];
    combine_half(cdA, cdB, t >= 32, v);
    return extract20_half(v, t);
}

// ---------------------------------------------------------------------------
// Stage 1 (R7 shape: 256 thr, 2 rows/wave, grid 1024, launch_bounds(256,4)).
// ---------------------------------------------------------------------------
__global__ __launch_bounds__(256, 4)
void stage1_kernel(const float* __restrict__ x, const float* __restrict__ w_fm1,
                   const float* __restrict__ w_fm2, const float* __restrict__ w_mix1,
                   const float* __restrict__ w_mix2, const float* __restrict__ m_last,
                   const float* __restrict__ b_cls,
                   float* __restrict__ R, float* __restrict__ sqr,
                   half8* __restrict__ Bfrag, f32x4* __restrict__ Mfrag,
                   float* __restrict__ out) {
    __shared__ float4 LxV[2048];        // 32 KB swizzled point tile (+scratch)
    __shared__ float ssq[512];
    __shared__ float swn[KNN];
    float* Lx = (float*)LxV;

    const int tid   = threadIdx.x;
    const int bidx  = blockIdx.x;
    const int batch = bidx >> 6;
    const float* xb = x + (size_t)batch * 8192;

    if ((bidx & 63) == 0 && tid < 40)
        out[batch * 40 + tid] = b_cls[tid];

    if (tid < KNN) {
        float v[KNN]; float mx = -__builtin_inff();
        #pragma unroll
        for (int k = 0; k < KNN; ++k) { v[k] = w_fm1[k]; mx = fmaxf(mx, v[k]); }
        float s = 0.f;
        #pragma unroll
        for (int k = 0; k < KNN; ++k) { v[k] = __expf(v[k] - mx); s += v[k]; }
        swn[tid] = v[tid] / s;
    }

    if (bidx == 0) {
        for (int e = tid; e < 1500; e += 256) Lx[e] = w_mix2[e];
        if (tid < 30) {
            float wr[KNN]; float mx = -__builtin_inff();
            #pragma unroll
            for (int k = 0; k < KNN; ++k) { wr[k] = w_fm2[tid * KNN + k]; mx = fmaxf(mx, wr[k]); }
            float s = 0.f;
            #pragma unroll
            for (int k = 0; k < KNN; ++k) { wr[k] = __expf(wr[k] - mx); s += wr[k]; }
            const float scale = w_mix1[tid] / s;
            #pragma unroll
            for (int k = 0; k < KNN; ++k) Lx[4096 + tid * 21 + k] = wr[k] * scale;
        }
    }
    __syncthreads();

    if (bidx == 0) {
        const int lane = tid & 63, tile = tid >> 6;
        const int q = lane >> 4, c = lane & 15;
        const int f = tile * 16 + c;
        half8 hb;
        #pragma unroll
        for (int j = 0; j < 8; ++j) {
            const int k = q * 8 + j;
            float val = 0.f;
            if (k < KNN && f < 50) {
                #pragma unroll
                for (int cc = 0; cc < 30; ++cc)
                    val = fmaf(Lx[4096 + cc * 21 + k], Lx[cc * 50 + f], val);
            }
            hb[j] = (_Float16)val;
        }
        Bfrag[tile * 64 + lane] = hb;
        f32x4 mf;
        #pragma unroll
        for (int r = 0; r < 4; ++r) {
            const int d = q * 4 + r;
            mf[r] = (f < 50) ? m_last[d * 50 + f] : 0.f;
        }
        Mfrag[tile * 64 + lane] = mf;
    }
    __syncthreads();   // Lx scratch fully consumed before restage

    {
        float4 creg[8];
        stage_tile(xb, Lx, tid, creg);
        const int m0 = tid * 2;
        ssq[m0]     = dot16(creg[0], creg[1], creg[2], creg[3],
                            creg[0], creg[1], creg[2], creg[3]);
        ssq[m0 + 1] = dot16(creg[4], creg[5], creg[6], creg[7],
                            creg[4], creg[5], creg[6], creg[7]);
    }
    __syncthreads();

    const int t = tid & 63, w = tid >> 6;
    const int n0 = (bidx & 63) * 8 + (w << 1);   // rows n0, n0+1
    const int n1 = n0 + 1;
    const size_t g0 = (size_t)batch * 512 + n0;
    const size_t g1 = g0 + 1;

    const float4* xa4 = (const float4*)(xb + n0 * 16);
    const float4 oa0 = xa4[0], oa1 = xa4[1], oa2 = xa4[2], oa3 = xa4[3];
    const float4* xb4 = (const float4*)(xb + n1 * 16);
    const float4 ob0 = xb4[0], ob1 = xb4[1], ob2 = xb4[2], ob3 = xb4[3];

    const int nbr = knn_select(Lx, ssq, ssq[n0], ssq[n1], t,
                               oa0, oa1, oa2, oa3, ob0, ob1, ob2, ob3);

    // gather from the LDS tile: lane covers e = j*64+t -> (k = e>>4, d = e&15)
    float nrfA[5], nrfB[5];
    #pragma unroll
    for (int j = 0; j < 5; ++j) {
        const int e = j * 64 + t;
        const int src = e >> 4;                       // rank, < 20
        const int nbA = __shfl(nbr, src, 64);         // row A ranks: lanes 0..19
        const int nbB = __shfl(nbr, src + 32, 64);    // row B ranks: lanes 32..51
        nrfA[j] = lds_elem(Lx, nbA, e & 15);
        nrfB[j] = lds_elem(Lx, nbB, e & 15);
    }
    // partial wFM: lane t sums its 5 k's for d = t&15 (k = j*4 + t>>4)
    const int kq = t >> 4;
    float pA = 0.f, pB = 0.f;
    #pragma unroll
    for (int j = 0; j < 5; ++j) {
        const float wv = swn[j * 4 + kq];
        pA = fmaf(wv, nrfA[j], pA);
        pB = fmaf(wv, nrfB[j], pB);
    }
    pA += __shfl_xor(pA, 16, 64); pB += __shfl_xor(pB, 16, 64);
    pA += __shfl_xor(pA, 32, 64); pB += __shfl_xor(pB, 32, 64);
    const float raccA = pA, raccB = pB;
    if (t < 16) {
        R[g0 * 16 + t] = raccA;
        R[g1 * 16 + t] = raccB;
    }

    // ||R||^2, shfl-parallel but with the SAME 4-chain fma grouping as dot16:
    // lanes 0..3 run row A's chains p0..p3 (sources raccA lanes 4L..4L+3, in
    // ascending order, acc start 0); lanes 4..7 run row B's. Combine
    // (p0+p1)+(p2+p3) on lanes 0 (A) and 4 (B). Bit-identical to the readlane
    // version (fma chain order and final add tree unchanged).
    {
        const float rbS = __shfl(raccB, t - 16, 64);      // lanes 16..31 <- raccB[t-16]
        const float val = (t < 16) ? raccA : rbS;         // junk elsewhere (unused)
        const int base = (t < 4) ? (t * 4) : (16 + (t - 4) * 4);
        const float v0 = __shfl(val, base + 0, 64);
        const float v1 = __shfl(val, base + 1, 64);
        const float v2 = __shfl(val, base + 2, 64);
        const float v3 = __shfl(val, base + 3, 64);
        float p = fmaf(v0, v0, 0.f);
        p = fmaf(v1, v1, p);
        p = fmaf(v2, v2, p);
        p = fmaf(v3, v3, p);
        const int cb = t & 60;
        const float q1 = __shfl(p, cb + 1, 64);
        const float q2 = __shfl(p, cb + 2, 64);
        const float q3 = __shfl(p, cb + 3, 64);
        const float ssum = (p + q1) + (q2 + q3);
        if (t == 0) sqr[g0] = ssum;
        if (t == 4) sqr[g1] = ssum;
    }
}

// ---------------------------------------------------------------------------
// Stage 2 (R7 shape): KNN on R + MFMA wFM2.mix2 + dist + pool + classify.
// ---------------------------------------------------------------------------
__global__ __launch_bounds__(256, 4)
void stage2_kernel(const float* __restrict__ Rg, const float* __restrict__ sqr,
                   const half8* __restrict__ Bfrag, const f32x4* __restrict__ Mfrag,
                   const float* __restrict__ w_cls, float* __restrict__ out) {
    __shared__ float4 LrV[2048];        // 32 KB swizzled R tile
    __shared__ float ssq2[512];
    __shared__ float pool8[8];
    float* Lr = (float*)LrV;

    const int tid   = threadIdx.x;
    const int bidx  = blockIdx.x;
    const int batch = bidx >> 6;
    const float* Rb = Rg + (size_t)batch * 8192;
    const float* sb = sqr + batch * 512;

    for (int m = tid; m < 512; m += 256) ssq2[m] = sb[m];
    {
        float4 creg[8];
        stage_tile(Rb, Lr, tid, creg);
    }
    __syncthreads();

    const int t = tid & 63, w = tid >> 6;
    const int n0 = (bidx & 63) * 8 + (w << 1);
    const int n1 = n0 + 1;

    const float4* ra4 = (const float4*)(Rb + n0 * 16);
    const float4 oa0 = ra4[0], oa1 = ra4[1], oa2 = ra4[2], oa3 = ra4[3];
    const float4* rb4 = (const float4*)(Rb + n1 * 16);
    const float4 ob0 = rb4[0], ob1 = rb4[1], ob2 = rb4[2], ob3 = rb4[3];

    const int nbr = knn_select(Lr, ssq2, ssq2[n0], ssq2[n1], t,
                               oa0, oa1, oa2, oa3, ob0, ob1, ob2, ob3);

    // A-fragments straight from the tile: A[m=t&15][k=(t>>4)*8+j] = NR[k][m]
    const int q = t >> 4, c = t & 15;
    half8 afA, afB;
    #pragma unroll
    for (int j = 0; j < 8; ++j) {
        const int k = q * 8 + j;
        const int nbA = __shfl(nbr, k & 31, 64);
        const int nbB = __shfl(nbr, (k & 31) + 32, 64);
        afA[j] = (k < KNN) ? (_Float16)lds_elem(Lr, nbA, c) : (_Float16)0.f;
        afB[j] = (k < KNN) ? (_Float16)lds_elem(Lr, nbB, c) : (_Float16)0.f;
    }

    // 4 f-tiles of 16: v = A(16x32) . B(32x16); dist accumulate (bf/mf shared)
    float dsumA = 0.f, dsumB = 0.f;
    #pragma unroll
    for (int tile = 0; tile < 4; ++tile) {
        const half8 bf = Bfrag[tile * 64 + t];
        const f32x4 mf = Mfrag[tile * 64 + t];
        f32x4 accA = {0.f, 0.f, 0.f, 0.f};
        f32x4 accB = {0.f, 0.f, 0.f, 0.f};
        accA = __builtin_amdgcn_mfma_f32_16x16x32_f16(afA, bf, accA, 0, 0, 0);
        accB = __builtin_amdgcn_mfma_f32_16x16x32_f16(afB, bf, accB, 0, 0, 0);
        float a2A = 0.f, a2B = 0.f;
        #pragma unroll
        for (int r = 0; r < 4; ++r) {
            const float dA = accA[r] - mf[r];
            const float dB = accB[r] - mf[r];
            a2A = fmaf(dA, dA, a2A);
            a2B = fmaf(dB, dB, a2B);
        }
        a2A += __shfl_xor(a2A, 16, 64); a2B += __shfl_xor(a2B, 16, 64);
        a2A += __shfl_xor(a2A, 32, 64); a2B += __shfl_xor(a2B, 32, 64);
        const int f = tile * 16 + c;
        dsumA += (f < 50) ? sqrtf(a2A + 1e-8f) : 0.f;
        dsumB += (f < 50) ? sqrtf(a2B + 1e-8f) : 0.f;
    }
    // wave sum counts each f 4x (column replication) -> /4; pooled = /50
    #pragma unroll
    for (int off = 32; off >= 1; off >>= 1) {
        dsumA += __shfl_xor(dsumA, off, 64);
        dsumB += __shfl_xor(dsumB, off, 64);
    }
    if (t == 0) {
        pool8[w * 2]     = dsumA * (1.0f / 200.0f);
        pool8[w * 2 + 1] = dsumB * (1.0f / 200.0f);
    }
    __syncthreads();

    if (tid < 40) {
        const int lb0 = (bidx & 63) * 8;
        float a = 0.f;
        #pragma unroll
        for (int i = 0; i < 8; ++i)
            a = fmaf(pool8[i], w_cls[(lb0 + i) * 40 + tid], a);
        unsafeAtomicAdd(&out[batch * 40 + tid], a);
    }
}

extern "C" void kernel_launch(void* const* d_in, const int* in_sizes, int n_in,
                              void* d_out, int out_size, void* d_ws, size_t ws_size,
                              hipStream_t stream) {
    const float* x      = (const float*)d_in[0];
    const float* w_fm1  = (const float*)d_in[1];
    const float* w_mix1 = (const float*)d_in[2];
    const float* w_fm2  = (const float*)d_in[3];
    const float* w_mix2 = (const float*)d_in[4];
    const float* m_last = (const float*)d_in[5];
    const float* w_cls  = (const float*)d_in[6];
    const float* b_cls  = (const float*)d_in[7];
    float* out = (float*)d_out;

    float* ws    = (float*)d_ws;
    float* R     = ws;                        // 131072 floats
    float* sqrb  = ws + 131072;               // 8192 floats
    half8* Bf    = (half8*)(ws + 139264);     // 256 x 16 B = 1024 floats
    f32x4* Mf    = (f32x4*)(ws + 140288);     // 256 x 16 B = 1024 floats

    stage1_kernel<<<1024, 256, 0, stream>>>(x, w_fm1, w_fm2, w_mix1, w_mix2,
                                            m_last, b_cls, R, sqrb, Bf, Mf, out);
    stage2_kernel<<<1024, 256, 0, stream>>>(R, sqrb, Bf, Mf, w_cls, out);
}

// Round 10
// 96.305 us; speedup vs baseline: 1.1186x; 1.0433x over previous
//
#include <hip/hip_runtime.h>
#include <math.h>

#define KNN  20
#define INFK 0xFFFFFFFFu

typedef _Float16 half8 __attribute__((ext_vector_type(8)));
typedef float    f32x4 __attribute__((ext_vector_type(4)));

#define CE(a, b)                                                               \
    { unsigned _lo = ((a) < (b)) ? (a) : (b);                                  \
      unsigned _hi = ((a) < (b)) ? (b) : (a); (a) = _lo; (b) = _hi; }

__device__ __forceinline__ void sort4(unsigned (&v)[4]) {
    CE(v[0], v[1]); CE(v[2], v[3]); CE(v[0], v[2]); CE(v[1], v[3]); CE(v[1], v[2]);
}

// Batcher odd-even merge of two sorted 4-lists -> sorted 8
__device__ __forceinline__ void merge44(unsigned (&a)[4], unsigned (&b)[4],
                                        unsigned (&o)[8]) {
    CE(a[0], b[0]); CE(a[1], b[1]); CE(a[2], b[2]); CE(a[3], b[3]);
    CE(a[2], b[0]); CE(a[3], b[1]);
    CE(a[1], a[2]); CE(a[3], b[0]); CE(b[1], b[2]);
    o[0] = a[0]; o[1] = a[1]; o[2] = a[2]; o[3] = a[3];
    o[4] = b[0]; o[5] = b[1]; o[6] = b[2]; o[7] = b[3];
}

// ---- sorted-quad keep-4 DPP combine (proven R5/R7) --------------------------
// x0..x3 sorted asc per lane; partner quad pulled via DPP (t0..t3 sorted asc).
// (x0..x3, t3..t0) is bitonic; CE at distance 4 keeps the 4 smallest, 4-CE
// bitonic fixup re-sorts. Disabled/out-of-bounds source lanes receive
// old = -1 = INFK -> identity combine.
template <int CTRL, int RM>
__device__ __forceinline__ void quadmin_step(unsigned& x0, unsigned& x1,
                                             unsigned& x2, unsigned& x3) {
    const unsigned t0 = (unsigned)__builtin_amdgcn_update_dpp(-1, (int)x0, CTRL, RM, 0xf, false);
    const unsigned t1 = (unsigned)__builtin_amdgcn_update_dpp(-1, (int)x1, CTRL, RM, 0xf, false);
    const unsigned t2 = (unsigned)__builtin_amdgcn_update_dpp(-1, (int)x2, CTRL, RM, 0xf, false);
    const unsigned t3 = (unsigned)__builtin_amdgcn_update_dpp(-1, (int)x3, CTRL, RM, 0xf, false);
    unsigned c0 = (x0 < t3) ? x0 : t3;
    unsigned c1 = (x1 < t2) ? x1 : t2;
    unsigned c2 = (x2 < t1) ? x2 : t1;
    unsigned c3 = (x3 < t0) ? x3 : t0;
    CE(c0, c2); CE(c1, c3); CE(c0, c1); CE(c2, c3);
    x0 = c0; x1 = c1; x2 = c2; x3 = c3;
}

// Half-wave quad-min: 5 DPP levels; lane 31 = row A's top-4, lane 63 = row B's.
__device__ __forceinline__ void halfwave_min4(unsigned x0, unsigned x1,
                                              unsigned x2, unsigned x3,
                                              unsigned (&wl)[4], unsigned (&wh)[4]) {
    quadmin_step<0x111, 0xf>(x0, x1, x2, x3);   // row_shr:1
    quadmin_step<0x112, 0xf>(x0, x1, x2, x3);   // row_shr:2
    quadmin_step<0x114, 0xf>(x0, x1, x2, x3);   // row_shr:4
    quadmin_step<0x118, 0xf>(x0, x1, x2, x3);   // row_shr:8
    quadmin_step<0x142, 0xa>(x0, x1, x2, x3);   // row_bcast:15 into rows 1,3
    wl[0] = (unsigned)__builtin_amdgcn_readlane((int)x0, 31);
    wl[1] = (unsigned)__builtin_amdgcn_readlane((int)x1, 31);
    wl[2] = (unsigned)__builtin_amdgcn_readlane((int)x2, 31);
    wl[3] = (unsigned)__builtin_amdgcn_readlane((int)x3, 31);
    wh[0] = (unsigned)__builtin_amdgcn_readlane((int)x0, 63);
    wh[1] = (unsigned)__builtin_amdgcn_readlane((int)x1, 63);
    wh[2] = (unsigned)__builtin_amdgcn_readlane((int)x2, 63);
    wh[3] = (unsigned)__builtin_amdgcn_readlane((int)x3, 63);
}

// conditional shift of the leading LEN entries by cnt (1,2,4 decomposition)
template <int LEN>
__device__ __forceinline__ void shift_list(unsigned (&cd)[16], int cnt) {
    const bool s1 = (cnt & 1) != 0;
    const bool s2 = (cnt & 2) != 0;
    const bool s4 = (cnt & 4) != 0;
    #pragma unroll
    for (int i = 0; i < LEN - 1; ++i) cd[i] = s1 ? cd[i + 1] : cd[i];
    cd[LEN - 1] = s1 ? INFK : cd[LEN - 1];
    #pragma unroll
    for (int i = 0; i < LEN - 2; ++i) cd[i] = s2 ? cd[i + 2] : cd[i];
    #pragma unroll
    for (int i = LEN - 2; i < LEN; ++i) cd[i] = s2 ? INFK : cd[i];
    #pragma unroll
    for (int i = 0; i < LEN - 4; ++i) cd[i] = s4 ? cd[i + 4] : cd[i];
    #pragma unroll
    for (int i = LEN - 4; i < LEN; ++i) cd[i] = s4 ? INFK : cd[i];
}

// one extraction round: winners 4r..4r+3 of each half land on lanes (t&31).
// Removal: any key <= 4th winner IS a winner (unique keys, exact threshold).
template <int LEN>
__device__ __forceinline__ void round_extract(unsigned (&cd)[16], int t, int r,
                                              int& nbr, bool hi) {
    unsigned wl[4], wh[4];
    halfwave_min4(cd[0], cd[1], cd[2], cd[3], wl, wh);
    const unsigned w0 = hi ? wh[0] : wl[0];
    const unsigned w1 = hi ? wh[1] : wl[1];
    const unsigned w2 = hi ? wh[2] : wl[2];
    const unsigned w3 = hi ? wh[3] : wl[3];
    const int idx = t & 31;
    nbr = (idx == 4 * r    ) ? (int)(w0 & 511u) : nbr;
    nbr = (idx == 4 * r + 1) ? (int)(w1 & 511u) : nbr;
    nbr = (idx == 4 * r + 2) ? (int)(w2 & 511u) : nbr;
    nbr = (idx == 4 * r + 3) ? (int)(w3 & 511u) : nbr;
    if (LEN > 0) {
        const int cnt = (int)(cd[0] <= w3) + (int)(cd[1] <= w3) +
                        (int)(cd[2] <= w3) + (int)(cd[3] <= w3);
        shift_list<(LEN > 0 ? LEN : 16)>(cd, cnt);
    }
}

// 20-rank extraction in 5 quad-rounds on per-half sorted-16 lists.
// Shift lengths 16/16/12/8 are adversarially safe: a lane's valid prefix
// always covers min(remaining winners, its remaining candidates).
__device__ __forceinline__ int extract20_half(unsigned (&cd)[16], int t) {
    int nbr = 0;
    const bool hi = (t >= 32);
    round_extract<16>(cd, t, 0, nbr, hi);
    round_extract<16>(cd, t, 1, nbr, hi);
    round_extract<12>(cd, t, 2, nbr, hi);
    round_extract<8> (cd, t, 3, nbr, hi);
    round_extract<0> (cd, t, 4, nbr, hi);
    return nbr;
}

// Redistribute: lanes 0-31 take row A, lanes 32-63 row B; bitonic merge
// 8+8 -> sorted-16 per lane. Coverage per half: 32 lanes x 16 = all 512.
__device__ __forceinline__ void combine_half(const unsigned (&cdA)[8],
                                             const unsigned (&cdB)[8],
                                             bool hi, unsigned (&v)[16]) {
    unsigned snd[8], own[8], rcv[8];
    #pragma unroll
    for (int i = 0; i < 8; ++i) {
        snd[i] = hi ? cdA[i] : cdB[i];   // what my partner needs
        own[i] = hi ? cdB[i] : cdA[i];   // what I keep
    }
    #pragma unroll
    for (int i = 0; i < 8; ++i)
        rcv[i] = (unsigned)__shfl_xor((int)snd[i], 32, 64);
    #pragma unroll
    for (int i = 0; i < 8; ++i) { v[i] = own[i]; v[8 + i] = rcv[7 - i]; }
    // bitonic merge-16 (asc own ++ desc rcv is bitonic)
    #pragma unroll
    for (int i = 0; i < 8; ++i) CE(v[i], v[i + 8]);
    #pragma unroll
    for (int i = 0; i < 4; ++i) { CE(v[i], v[i + 4]); CE(v[i + 8], v[i + 12]); }
    #pragma unroll
    for (int b = 0; b < 16; b += 4) { CE(v[b], v[b + 2]); CE(v[b + 1], v[b + 3]); }
    #pragma unroll
    for (int p = 0; p < 16; p += 2) CE(v[p], v[p + 1]);
}

// canonical 4-chain dot; EVERY sq/dot uses this -> m==n diagonal exactly 0
__device__ __forceinline__ float dot16(const float4& o0, const float4& o1,
                                       const float4& o2, const float4& o3,
                                       const float4& a0, const float4& a1,
                                       const float4& a2, const float4& a3) {
    float d0 = 0.f, d1 = 0.f, d2 = 0.f, d3 = 0.f;
    d0 = fmaf(o0.x, a0.x, d0); d0 = fmaf(o0.y, a0.y, d0); d0 = fmaf(o0.z, a0.z, d0); d0 = fmaf(o0.w, a0.w, d0);
    d1 = fmaf(o1.x, a1.x, d1); d1 = fmaf(o1.y, a1.y, d1); d1 = fmaf(o1.z, a1.z, d1); d1 = fmaf(o1.w, a1.w, d1);
    d2 = fmaf(o2.x, a2.x, d2); d2 = fmaf(o2.y, a2.y, d2); d2 = fmaf(o2.z, a2.z, d2); d2 = fmaf(o2.w, a2.w, d2);
    d3 = fmaf(o3.x, a3.x, d3); d3 = fmaf(o3.y, a3.y, d3); d3 = fmaf(o3.z, a3.z, d3); d3 = fmaf(o3.w, a3.w, d3);
    return (d0 + d1) + (d2 + d3);
}

// ---------------------------------------------------------------------------
// Swizzled LDS tile: point m (16 f32 = 4 float4 chunks) lives at float index
// m*16, with chunk c stored in slot ((c + (m>>1)) & 3). Every access stays
// 16-B aligned (true ds_read/write_b128); the scan's 64-lane b128 reads land
// uniformly 8-deep on all 32 banks (hardware minimum).
// ---------------------------------------------------------------------------
__device__ __forceinline__ void stage_tile(const float* __restrict__ src,
                                           float* __restrict__ Lx, int tid,
                                           float4 (&c)[8]) {
    const float4* s = (const float4*)(src + tid * 32);
    #pragma unroll
    for (int i = 0; i < 8; ++i) c[i] = s[i];
    const int r = tid & 3;
    float* wp = Lx + tid * 32;
    *(float4*)(wp +      ((0 + r) & 3) * 4) = c[0];
    *(float4*)(wp +      ((1 + r) & 3) * 4) = c[1];
    *(float4*)(wp +      ((2 + r) & 3) * 4) = c[2];
    *(float4*)(wp +      ((3 + r) & 3) * 4) = c[3];
    *(float4*)(wp + 16 + ((0 + r) & 3) * 4) = c[4];
    *(float4*)(wp + 16 + ((1 + r) & 3) * 4) = c[5];
    *(float4*)(wp + 16 + ((2 + r) & 3) * 4) = c[6];
    *(float4*)(wp + 16 + ((3 + r) & 3) * 4) = c[7];
}

// scalar element read from the swizzled tile (gather paths)
__device__ __forceinline__ float lds_elem(const float* __restrict__ Lx,
                                          int m, int d) {
    const int cc  = d >> 2;
    const int rot = (cc + (m >> 1)) & 3;
    return Lx[m * 16 + rot * 4 + (d & 3)];
}

// candidate scan for TWO rows sharing every LDS read: 8 keys/lane/row,
// sorted-8 per row via sort4+sort4+merge44. Distance bits identical to all
// previous passing rounds (same dot16 chains, same inputs). Scalar fma form
// (R7): the R9 packed-f32x2 variant regressed (op-pair array = +32 VGPR live
// state in the hot loop; splats didn't fold into op_sel).
__device__ __forceinline__ void scan2_lds(const float* __restrict__ Lx,
                                          const float* __restrict__ ssq,
                                          float sqnA, float sqnB, int t,
                                          const float4& oa0, const float4& oa1,
                                          const float4& oa2, const float4& oa3,
                                          const float4& ob0, const float4& ob1,
                                          const float4& ob2, const float4& ob3,
                                          unsigned (&cdA)[8], unsigned (&cdB)[8]) {
    unsigned kA0[4], kA1[4], kB0[4], kB1[4];
    const int hrot = (t >> 1) & 3;
    const float* p0 = Lx + t * 16 + ((0 + hrot) & 3) * 4;
    const float* p1 = Lx + t * 16 + ((1 + hrot) & 3) * 4;
    const float* p2 = Lx + t * 16 + ((2 + hrot) & 3) * 4;
    const float* p3 = Lx + t * 16 + ((3 + hrot) & 3) * 4;
    #pragma unroll
    for (int j = 0; j < 8; ++j) {
        const int m = j * 64 + t;
        const float4 a0 = *(const float4*)(p0 + j * 1024);
        const float4 a1 = *(const float4*)(p1 + j * 1024);
        const float4 a2 = *(const float4*)(p2 + j * 1024);
        const float4 a3 = *(const float4*)(p3 + j * 1024);
        const float sm = ssq[m];
        const float dotA = dot16(oa0, oa1, oa2, oa3, a0, a1, a2, a3);
        const float dotB = dot16(ob0, ob1, ob2, ob3, a0, a1, a2, a3);
        float vdA = fmaxf(sqnA + sm - 2.f * dotA, 0.f);   // exact 0 at m==n
        float vdB = fmaxf(sqnB + sm - 2.f * dotB, 0.f);
        const unsigned keyA = (__float_as_uint(vdA) & 0xFFFFFE00u) | (unsigned)m;
        const unsigned keyB = (__float_as_uint(vdB) & 0xFFFFFE00u) | (unsigned)m;
        if (j < 4) { kA0[j] = keyA; kB0[j] = keyB; }
        else       { kA1[j - 4] = keyA; kB1[j - 4] = keyB; }
    }
    sort4(kA0); sort4(kA1); sort4(kB0); sort4(kB1);
    merge44(kA0, kA1, cdA);
    merge44(kB0, kB1, cdB);
}

// full selection: scan -> redistribute halves -> 5-round quad extraction.
// Returns nbr: lanes 0..19 hold row A ranks 0..19, lanes 32..51 row B's.
__device__ __forceinline__ int knn_select(const float* __restrict__ Lx,
                                          const float* __restrict__ ssq,
                                          float sqnA, float sqnB, int t,
                                          const float4& oa0, const float4& oa1,
                                          const float4& oa2, const float4& oa3,
                                          const float4& ob0, const float4& ob1,
                                          const float4& ob2, const float4& ob3) {
    unsigned cdA[8], cdB[8];
    scan2_lds(Lx, ssq, sqnA, sqnB, t,
              oa0, oa1, oa2, oa3, ob0, ob1, ob2, ob3, cdA, cdB);
    unsigned v[16];
    combine_half(cdA, cdB, t >= 32, v);
    return extract20_half(v, t);
}

// ---------------------------------------------------------------------------
// Stage 1 (R7 shape: 256 thr, 2 rows/wave, grid 1024, launch_bounds(256,4);
// occupancy LDS-bound at 4 blocks/CU, so the 128-VGPR cap costs nothing and
// kills spills). ||R||^2 epilogue is the R9 shfl-parallel version (HW-verified
// bit-identical): replaces 64 serial readlane+fma with ~20 instructions.
// ---------------------------------------------------------------------------
__global__ __launch_bounds__(256, 4)
void stage1_kernel(const float* __restrict__ x, const float* __restrict__ w_fm1,
                   const float* __restrict__ w_fm2, const float* __restrict__ w_mix1,
                   const float* __restrict__ w_mix2, const float* __restrict__ m_last,
                   const float* __restrict__ b_cls,
                   float* __restrict__ R, float* __restrict__ sqr,
                   half8* __restrict__ Bfrag, f32x4* __restrict__ Mfrag,
                   float* __restrict__ out) {
    __shared__ float4 LxV[2048];        // 32 KB swizzled point tile (+scratch)
    __shared__ float ssq[512];
    __shared__ float swn[KNN];
    float* Lx = (float*)LxV;

    const int tid   = threadIdx.x;
    const int bidx  = blockIdx.x;
    const int batch = bidx >> 6;
    const float* xb = x + (size_t)batch * 8192;

    if ((bidx & 63) == 0 && tid < 40)
        out[batch * 40 + tid] = b_cls[tid];

    if (tid < KNN) {
        float v[KNN]; float mx = -__builtin_inff();
        #pragma unroll
        for (int k = 0; k < KNN; ++k) { v[k] = w_fm1[k]; mx = fmaxf(mx, v[k]); }
        float s = 0.f;
        #pragma unroll
        for (int k = 0; k < KNN; ++k) { v[k] = __expf(v[k] - mx); s += v[k]; }
        swn[tid] = v[tid] / s;
    }

    if (bidx == 0) {
        // scratch layout inside Lx (consumed before the tile is staged):
        //   smix2 = Lx[0..1499], wcs = Lx[4096 + c*21 + k] (30x21)
        for (int e = tid; e < 1500; e += 256) Lx[e] = w_mix2[e];
        if (tid < 30) {
            float wr[KNN]; float mx = -__builtin_inff();
            #pragma unroll
            for (int k = 0; k < KNN; ++k) { wr[k] = w_fm2[tid * KNN + k]; mx = fmaxf(mx, wr[k]); }
            float s = 0.f;
            #pragma unroll
            for (int k = 0; k < KNN; ++k) { wr[k] = __expf(wr[k] - mx); s += wr[k]; }
            const float scale = w_mix1[tid] / s;
            #pragma unroll
            for (int k = 0; k < KNN; ++k) Lx[4096 + tid * 21 + k] = wr[k] * scale;
        }
    }
    __syncthreads();

    if (bidx == 0) {
        // Per-lane fragment tables for stage2's mfma_f32_16x16x32_f16:
        //   A[m=lane&15][k=(lane>>4)*8+j], B[k=(lane>>4)*8+j][n=lane&15],
        //   C/D: col=lane&15, row=(lane>>4)*4+reg.
        const int lane = tid & 63, tile = tid >> 6;
        const int q = lane >> 4, c = lane & 15;
        const int f = tile * 16 + c;
        half8 hb;
        #pragma unroll
        for (int j = 0; j < 8; ++j) {
            const int k = q * 8 + j;
            float val = 0.f;
            if (k < KNN && f < 50) {
                #pragma unroll
                for (int cc = 0; cc < 30; ++cc)
                    val = fmaf(Lx[4096 + cc * 21 + k], Lx[cc * 50 + f], val);
            }
            hb[j] = (_Float16)val;
        }
        Bfrag[tile * 64 + lane] = hb;
        f32x4 mf;
        #pragma unroll
        for (int r = 0; r < 4; ++r) {
            const int d = q * 4 + r;
            mf[r] = (f < 50) ? m_last[d * 50 + f] : 0.f;
        }
        Mfrag[tile * 64 + lane] = mf;
    }
    __syncthreads();   // Lx scratch fully consumed before restage

    // stage points into swizzled LDS; ssq from the staging registers
    {
        float4 creg[8];
        stage_tile(xb, Lx, tid, creg);
        const int m0 = tid * 2;
        ssq[m0]     = dot16(creg[0], creg[1], creg[2], creg[3],
                            creg[0], creg[1], creg[2], creg[3]);
        ssq[m0 + 1] = dot16(creg[4], creg[5], creg[6], creg[7],
                            creg[4], creg[5], creg[6], creg[7]);
    }
    __syncthreads();

    const int t = tid & 63, w = tid >> 6;
    const int n0 = (bidx & 63) * 8 + (w << 1);   // rows n0, n0+1
    const int n1 = n0 + 1;
    const size_t g0 = (size_t)batch * 512 + n0;
    const size_t g1 = g0 + 1;

    const float4* xa4 = (const float4*)(xb + n0 * 16);
    const float4 oa0 = xa4[0], oa1 = xa4[1], oa2 = xa4[2], oa3 = xa4[3];
    const float4* xb4 = (const float4*)(xb + n1 * 16);
    const float4 ob0 = xb4[0], ob1 = xb4[1], ob2 = xb4[2], ob3 = xb4[3];

    const int nbr = knn_select(Lx, ssq, ssq[n0], ssq[n1], t,
                               oa0, oa1, oa2, oa3, ob0, ob1, ob2, ob3);

    // gather from the LDS tile: lane covers e = j*64+t -> (k = e>>4, d = e&15)
    float nrfA[5], nrfB[5];
    #pragma unroll
    for (int j = 0; j < 5; ++j) {
        const int e = j * 64 + t;
        const int src = e >> 4;                       // rank, < 20
        const int nbA = __shfl(nbr, src, 64);         // row A ranks: lanes 0..19
        const int nbB = __shfl(nbr, src + 32, 64);    // row B ranks: lanes 32..51
        nrfA[j] = lds_elem(Lx, nbA, e & 15);
        nrfB[j] = lds_elem(Lx, nbB, e & 15);
    }
    // partial wFM: lane t sums its 5 k's for d = t&15 (k = j*4 + t>>4)
    const int kq = t >> 4;
    float pA = 0.f, pB = 0.f;
    #pragma unroll
    for (int j = 0; j < 5; ++j) {
        const float wv = swn[j * 4 + kq];
        pA = fmaf(wv, nrfA[j], pA);
        pB = fmaf(wv, nrfB[j], pB);
    }
    pA += __shfl_xor(pA, 16, 64); pB += __shfl_xor(pB, 16, 64);
    pA += __shfl_xor(pA, 32, 64); pB += __shfl_xor(pB, 32, 64);
    const float raccA = pA, raccB = pB;
    if (t < 16) {
        R[g0 * 16 + t] = raccA;
        R[g1 * 16 + t] = raccB;
    }

    // ||R||^2, shfl-parallel with the SAME 4-chain fma grouping as dot16:
    // lanes 0..3 run row A's chains p0..p3 (sources raccA lanes 4L..4L+3 in
    // ascending order, acc start 0); lanes 4..7 run row B's. Combine
    // (p0+p1)+(p2+p3) on lanes 0 (A) and 4 (B). Bit-identical to the readlane
    // version (HW-verified in R9: absmax unchanged).
    {
        const float rbS = __shfl(raccB, t - 16, 64);      // lanes 16..31 <- raccB[t-16]
        const float val = (t < 16) ? raccA : rbS;         // junk elsewhere (unused)
        const int base = (t < 4) ? (t * 4) : (16 + (t - 4) * 4);
        const float v0 = __shfl(val, base + 0, 64);
        const float v1 = __shfl(val, base + 1, 64);
        const float v2 = __shfl(val, base + 2, 64);
        const float v3 = __shfl(val, base + 3, 64);
        float p = fmaf(v0, v0, 0.f);
        p = fmaf(v1, v1, p);
        p = fmaf(v2, v2, p);
        p = fmaf(v3, v3, p);
        const int cb = t & 60;
        const float q1 = __shfl(p, cb + 1, 64);
        const float q2 = __shfl(p, cb + 2, 64);
        const float q3 = __shfl(p, cb + 3, 64);
        const float ssum = (p + q1) + (q2 + q3);
        if (t == 0) sqr[g0] = ssum;
        if (t == 4) sqr[g1] = ssum;
    }
}

// ---------------------------------------------------------------------------
// Stage 2 (R7 shape): KNN on R + MFMA wFM2.mix2 + dist + pool + classify.
// Two rows per wave; Bfrag/Mfrag tile loads shared between the rows.
// ---------------------------------------------------------------------------
__global__ __launch_bounds__(256, 4)
void stage2_kernel(const float* __restrict__ Rg, const float* __restrict__ sqr,
                   const half8* __restrict__ Bfrag, const f32x4* __restrict__ Mfrag,
                   const float* __restrict__ w_cls, float* __restrict__ out) {
    __shared__ float4 LrV[2048];        // 32 KB swizzled R tile
    __shared__ float ssq2[512];
    __shared__ float pool8[8];
    float* Lr = (float*)LrV;

    const int tid   = threadIdx.x;
    const int bidx  = blockIdx.x;
    const int batch = bidx >> 6;
    const float* Rb = Rg + (size_t)batch * 8192;
    const float* sb = sqr + batch * 512;

    for (int m = tid; m < 512; m += 256) ssq2[m] = sb[m];
    {
        float4 creg[8];
        stage_tile(Rb, Lr, tid, creg);
    }
    __syncthreads();

    const int t = tid & 63, w = tid >> 6;
    const int n0 = (bidx & 63) * 8 + (w << 1);
    const int n1 = n0 + 1;

    const float4* ra4 = (const float4*)(Rb + n0 * 16);
    const float4 oa0 = ra4[0], oa1 = ra4[1], oa2 = ra4[2], oa3 = ra4[3];
    const float4* rb4 = (const float4*)(Rb + n1 * 16);
    const float4 ob0 = rb4[0], ob1 = rb4[1], ob2 = rb4[2], ob3 = rb4[3];

    const int nbr = knn_select(Lr, ssq2, ssq2[n0], ssq2[n1], t,
                               oa0, oa1, oa2, oa3, ob0, ob1, ob2, ob3);

    // A-fragments straight from the tile: A[m=t&15][k=(t>>4)*8+j] = NR[k][m]
    // (nbr is 0 on non-rank lanes, so masked shfl sources stay in-bounds)
    const int q = t >> 4, c = t & 15;
    half8 afA, afB;
    #pragma unroll
    for (int j = 0; j < 8; ++j) {
        const int k = q * 8 + j;
        const int nbA = __shfl(nbr, k & 31, 64);
        const int nbB = __shfl(nbr, (k & 31) + 32, 64);
        afA[j] = (k < KNN) ? (_Float16)lds_elem(Lr, nbA, c) : (_Float16)0.f;
        afB[j] = (k < KNN) ? (_Float16)lds_elem(Lr, nbB, c) : (_Float16)0.f;
    }

    // 4 f-tiles of 16: v = A(16x32) . B(32x16); dist accumulate (bf/mf shared)
    float dsumA = 0.f, dsumB = 0.f;
    #pragma unroll
    for (int tile = 0; tile < 4; ++tile) {
        const half8 bf = Bfrag[tile * 64 + t];
        const f32x4 mf = Mfrag[tile * 64 + t];
        f32x4 accA = {0.f, 0.f, 0.f, 0.f};
        f32x4 accB = {0.f, 0.f, 0.f, 0.f};
        accA = __builtin_amdgcn_mfma_f32_16x16x32_f16(afA, bf, accA, 0, 0, 0);
        accB = __builtin_amdgcn_mfma_f32_16x16x32_f16(afB, bf, accB, 0, 0, 0);
        float a2A = 0.f, a2B = 0.f;
        #pragma unroll
        for (int r = 0; r < 4; ++r) {
            const float dA = accA[r] - mf[r];
            const float dB = accB[r] - mf[r];
            a2A = fmaf(dA, dA, a2A);
            a2B = fmaf(dB, dB, a2B);
        }
        a2A += __shfl_xor(a2A, 16, 64); a2B += __shfl_xor(a2B, 16, 64);
        a2A += __shfl_xor(a2A, 32, 64); a2B += __shfl_xor(a2B, 32, 64);
        const int f = tile * 16 + c;
        dsumA += (f < 50) ? sqrtf(a2A + 1e-8f) : 0.f;
        dsumB += (f < 50) ? sqrtf(a2B + 1e-8f) : 0.f;
    }
    // wave sum counts each f 4x (column replication) -> /4; pooled = /50
    #pragma unroll
    for (int off = 32; off >= 1; off >>= 1) {
        dsumA += __shfl_xor(dsumA, off, 64);
        dsumB += __shfl_xor(dsumB, off, 64);
    }
    if (t == 0) {
        pool8[w * 2]     = dsumA * (1.0f / 200.0f);
        pool8[w * 2 + 1] = dsumB * (1.0f / 200.0f);
    }
    __syncthreads();

    if (tid < 40) {
        const int lb0 = (bidx & 63) * 8;
        float a = 0.f;
        #pragma unroll
        for (int i = 0; i < 8; ++i)
            a = fmaf(pool8[i], w_cls[(lb0 + i) * 40 + tid], a);
        unsafeAtomicAdd(&out[batch * 40 + tid], a);
    }
}

extern "C" void kernel_launch(void* const* d_in, const int* in_sizes, int n_in,
                              void* d_out, int out_size, void* d_ws, size_t ws_size,
                              hipStream_t stream) {
    const float* x      = (const float*)d_in[0];
    const float* w_fm1  = (const float*)d_in[1];
    const float* w_mix1 = (const float*)d_in[2];
    const float* w_fm2  = (const float*)d_in[3];
    const float* w_mix2 = (const float*)d_in[4];
    const float* m_last = (const float*)d_in[5];
    const float* w_cls  = (const float*)d_in[6];
    const float* b_cls  = (const float*)d_in[7];
    float* out = (float*)d_out;

    float* ws    = (float*)d_ws;
    float* R     = ws;                        // 131072 floats
    float* sqrb  = ws + 131072;               // 8192 floats
    half8* Bf    = (half8*)(ws + 139264);     // 256 x 16 B = 1024 floats
    f32x4* Mf    = (f32x4*)(ws + 140288);     // 256 x 16 B = 1024 floats

    stage1_kernel<<<1024, 256, 0, stream>>>(x, w_fm1, w_fm2, w_mix1, w_mix2,
                                            m_last, b_cls, R, sqrb, Bf, Mf, out);
    stage2_kernel<<<1024, 256, 0, stream>>>(R, sqrb, Bf, Mf, w_cls, out);
}